// Round 7
// baseline (451.620 us; speedup 1.0000x reference)
//
#include <hip/hip_runtime.h>
#include <math.h>

#define SLATE 20
#define DD 256
#define NSEQ 4096

typedef __attribute__((ext_vector_type(8))) short bf16x8;
typedef __attribute__((ext_vector_type(4))) float f32x4;
typedef unsigned short u16;
typedef unsigned int u32;

__device__ __forceinline__ u16 f2bf(float f) {
    unsigned u = __float_as_uint(f);
    u += 0x7fff + ((u >> 16) & 1);   // RNE
    return (u16)(u >> 16);
}
__device__ __forceinline__ float blo(u32 u) { return __uint_as_float(u << 16); }
__device__ __forceinline__ float bhi(u32 u) { return __uint_as_float(u & 0xffff0000u); }
// HW transcendentals: saturate correctly at +-inf, no NaN
__device__ __forceinline__ float sigm_(float x) {
    return __builtin_amdgcn_rcpf(1.f + __builtin_amdgcn_exp2f(-1.44269504f * x));
}
__device__ __forceinline__ float tanh_(float x) {
    return 1.f - 2.f * __builtin_amdgcn_rcpf(1.f + __builtin_amdgcn_exp2f(2.88539008f * x));
}

// async global->LDS, 16B per lane
__device__ __forceinline__ void gl_lds16(const void* g, void* l) {
    __builtin_amdgcn_global_load_lds(
        (const __attribute__((address_space(1))) unsigned int*)g,
        (__attribute__((address_space(3))) unsigned int*)l, 16, 0, 0);
}

// ---- prep: W12[j<768][k]=W_ih[j][k]; W12[768+j][k]=W_ih[j][256+k]; Whh bf16
__global__ void prep_w(const float* __restrict__ W_ih, const float* __restrict__ W_hh,
                       u16* __restrict__ W12, u16* __restrict__ Whh) {
    int i = blockIdx.x * 256 + threadIdx.x;
    if (i < 1536 * 256) {
        int j = i >> 8, k = i & 255;
        float v = (j < 768) ? W_ih[(size_t)j * 512 + k]
                            : W_ih[(size_t)(j - 768) * 512 + 256 + k];
        W12[i] = f2bf(v);
    } else {
        int i2 = i - 1536 * 256;
        Whh[i2] = f2bf(W_hh[i2]);
    }
}

// ---- gather chunk embeddings to bf16, M-order = [s_local][n]
__global__ void gather_e(int s0, const int* __restrict__ idxs, const float* __restrict__ itab,
                         u16* __restrict__ e_bf) {
    int g = blockIdx.x * 256 + threadIdx.x;
    int row = g >> 6, c = g & 63;
    int n = row & (NSEQ - 1), s = s0 + (row >> 12);
    int idx = idxs[n * SLATE + s];
    float4 v = *(const float4*)&itab[(size_t)idx * DD + c * 4];
    ushort4 o;
    o.x = f2bf(v.x); o.y = f2bf(v.y); o.z = f2bf(v.z); o.w = f2bf(v.w);
    *(ushort4*)&e_bf[(size_t)row * DD + c * 4] = o;
}

// ---- hoisted GEMM: EXACT R2 form (measured 65 us). stage -> sync -> compute -> sync,
// 128x128 tile, 2D grid, scalar u16 epilogue. Every restructure attempt (depth-2
// pipeline, 256M tile, uint2 epilogue + 1D XCD swizzle) measured WORSE - do not touch.
// Epilogue folds b_ih (cols<768) + b_hh (r,z cols<512); gate-n b_hh stays in seq.
__global__ __launch_bounds__(256) void gemm_e(
        const u16* __restrict__ e_bf, const u16* __restrict__ W12,
        const float* __restrict__ b_ih, const float* __restrict__ b_hh,
        u16* __restrict__ Ge) {
    __shared__ u16 A_s[128][32];
    __shared__ u16 B_s[128][32];

    const int tid = threadIdx.x;
    const int w = tid >> 6, l = tid & 63, lm = l & 15, lq = l >> 4;
    const int wm = w & 1, wn = w >> 1;
    const size_t m0 = (size_t)blockIdx.y * 128;
    const size_t n0 = (size_t)blockIdx.x * 128;

    f32x4 acc[4][4];
    f32x4 zero4 = {0.f, 0.f, 0.f, 0.f};
#pragma unroll
    for (int mi = 0; mi < 4; ++mi)
#pragma unroll
        for (int nj = 0; nj < 4; ++nj) acc[mi][nj] = zero4;

    const int srow = w * 16 + (l >> 2);
    const int skc = (l & 3) * 8;
    const u16* gA = e_bf + (m0 + srow) * DD + skc;
    const u16* gB = W12 + (n0 + srow) * DD + skc;
    u16* lA = &A_s[0][0] + w * 512 + l * 8;
    u16* lB = &B_s[0][0] + w * 512 + l * 8;

    for (int kt = 0; kt < 8; ++kt) {
        const int ko = kt * 32;
        gl_lds16(gA + ko, lA);
        gl_lds16(gA + 64 * DD + ko, lA + 2048);
        gl_lds16(gB + ko, lB);
        gl_lds16(gB + 64 * DD + ko, lB + 2048);
        __syncthreads();
        bf16x8 af[4], bfr[4];
#pragma unroll
        for (int mi = 0; mi < 4; ++mi)
            af[mi] = *(const bf16x8*)&A_s[wm * 64 + mi * 16 + lm][lq * 8];
#pragma unroll
        for (int nj = 0; nj < 4; ++nj)
            bfr[nj] = *(const bf16x8*)&B_s[wn * 64 + nj * 16 + lm][lq * 8];
#pragma unroll
        for (int nj = 0; nj < 4; ++nj)
#pragma unroll
            for (int mi = 0; mi < 4; ++mi)
                acc[mi][nj] = __builtin_amdgcn_mfma_f32_16x16x32_bf16(af[mi], bfr[nj], acc[mi][nj], 0, 0, 0);
        __syncthreads();
    }
    float bb[4];
#pragma unroll
    for (int nj = 0; nj < 4; ++nj) {
        int col = (int)n0 + wn * 64 + nj * 16 + lm;
        bb[nj] = 0.f;
        if (col < 768) bb[nj] = b_ih[col] + (col < 512 ? b_hh[col] : 0.f);
    }
#pragma unroll
    for (int mi = 0; mi < 4; ++mi)
#pragma unroll
        for (int rr = 0; rr < 4; ++rr) {
            u16* gp = Ge + (m0 + wm * 64 + mi * 16 + lq * 4 + rr) * 1536 + n0 + wn * 64 + lm;
#pragma unroll
            for (int nj = 0; nj < 4; ++nj) gp[nj * 16] = f2bf(acc[mi][nj][rr] + bb[nj]);
        }
}

// swizzled hA: logical (seq, k) -> u16 offset; v spreads banks for both access patterns
__device__ __forceinline__ int hA_off(int seq, int kt, int lq2) {
    int v = ((kt & 3) << 2) | lq2;
    return kt * 512 + lq2 * 128 + ((seq ^ v) << 3);
}

// ---- fused sequential kernel: 512 blocks x 8 seqs, 512 threads (8 waves).
// CHANGE vs R2: block halved (8 seqs) -> LDS = 8 + 24 + 48 = 80.0 KB = EXACTLY
// 2 blocks/CU (was 152 KB -> 1 block/CU). Mechanism: doubles per-CU outstanding
// Ge-stream loads + overlaps one block's GEMM with the other's combine; also
// sheds ~28 VGPRs (h_reg/wo/ge temps halve) off the previous ~256-edge budget.
// GEMM per-wave geometry unchanged (96 cols, warr 192 VGPR, pure LDS+VGPR);
// hA keeps 16 M-rows (rows 8-15 zeroed once) so MFMA tiles are unchanged.
__global__ __launch_bounds__(512, 2) void seq_kernel(
        int s0, int C,
        const u16* __restrict__ Ge,     // [C*4096][1536] (b_ih + b_hh(r,z) pre-folded)
        const u16* __restrict__ Whh,    // [768][256] bf16
        const int* __restrict__ user_idxs, const float* __restrict__ user_table,
        const float* __restrict__ b_hh,
        const float* __restrict__ W_out, const float* __restrict__ b_out,
        float* __restrict__ h_g, float* __restrict__ m_g, float* __restrict__ out)
{
    __shared__ u16   hA[4096];          // 8 KB: 16 M-slots (8 seqs + 8 zero rows)
    __shared__ float gh_s[8][768];      // 24 KB (unpadded; write conflict negligible)
    __shared__ u16   geL[2][8][1536];   // 48 KB double-buffered Ge slab

    const int tid = threadIdx.x;
    const int w = tid >> 6, l = tid & 63, lm = l & 15, lq = l >> 4;
    const int n0 = blockIdx.x * 8;
    const int nw = n0 + w;              // combine: wave w -> seq w
    const int jw2 = w * 96;             // GEMM: each wave owns 96 N-cols

    // ---- Whh fully VGPR-resident: 6 fragments x 8 k-steps = 192 regs
    bf16x8 warr[6][8];
    const u16* wb = Whh + (size_t)(jw2 + lm) * DD + lq * 8;
#pragma unroll
    for (int fi = 0; fi < 6; ++fi)
#pragma unroll
        for (int kt = 0; kt < 8; ++kt)
            warr[fi][kt] = *(const bf16x8*)(wb + fi * 16 * DD + kt * 32);

    // gate-n b_hh (cols >= 512 only; wave-uniform condition per fragment)
    float bn[6];
#pragma unroll
    for (int fi = 0; fi < 6; ++fi) {
        int colb = jw2 + fi * 16;
        bn[fi] = (colb >= 512) ? b_hh[colb + lm] : 0.f;
    }

    // W_out per-lane (lane's 4 features: 2l+128j, +1; j=0,1)
    float wo[4];
#pragma unroll
    for (int j = 0; j < 2; ++j) {
        float2 t = *(const float2*)&W_out[2 * l + 128 * j];
        wo[2 * j] = t.x; wo[2 * j + 1] = t.y;
    }
    const float bo = b_out[0];

    // ---- init h (4 feats/lane) ----
    float h_reg[4]; float m_w;
    if (s0 == 0) {
        const float* hu = user_table + (size_t)user_idxs[nw] * DD;
#pragma unroll
        for (int j = 0; j < 2; ++j) {
            float2 t = *(const float2*)&hu[2 * l + 128 * j];
            h_reg[2 * j] = t.x; h_reg[2 * j + 1] = t.y;
        }
        m_w = 1.f;
    } else {
        const float* hp = h_g + (size_t)nw * DD;
#pragma unroll
        for (int j = 0; j < 2; ++j) {
            float2 t = *(const float2*)&hp[2 * l + 128 * j];
            h_reg[2 * j] = t.x; h_reg[2 * j + 1] = t.y;
        }
        m_w = m_g[nw];
    }
    // hA init: k = 2l + 128j -> (kt=(l>>4)+4j, lq2=(l>>2)&3, pos=2*(l&3));
    // also zero the pad slot (w+8) so MFMA M-rows 8-15 are inert.
#pragma unroll
    for (int j = 0; j < 2; ++j) {
        int ktw = (l >> 4) + 4 * j, lq2 = (l >> 2) & 3;
        u32 pk = (u32)f2bf(h_reg[2 * j]) | ((u32)f2bf(h_reg[2 * j + 1]) << 16);
        *(u32*)&hA[hA_off(w, ktw, lq2) + 2 * (l & 3)] = pk;
        *(u32*)&hA[hA_off(w + 8, ktw, lq2) + 2 * (l & 3)] = 0u;
    }

    // ---- prologue: stage slab 0 (24 KB contiguous, 3 x 16B per thread)
    {
        const u16* g0 = Ge + (size_t)n0 * 1536;
        u16* l0 = &geL[0][0][0];
#pragma unroll
        for (int i = 0; i < 3; ++i)
            gl_lds16(g0 + tid * 8 + i * 4096, l0 + tid * 8 + i * 4096);
    }
    asm volatile("s_waitcnt lgkmcnt(0)" ::: "memory");
    __builtin_amdgcn_s_barrier();
    __builtin_amdgcn_sched_barrier(0);

    for (int sc = 0; sc < C; ++sc) {
        const int cur = sc & 1;

        // ---- prefetch NEXT step's slab at top of step: full-step cover
        if (sc + 1 < C) {
            const u16* gn = Ge + ((size_t)(sc + 1) * NSEQ + n0) * 1536;
            u16* ln = &geL[cur ^ 1][0][0];
#pragma unroll
            for (int i = 0; i < 3; ++i)
                gl_lds16(gn + tid * 8 + i * 4096, ln + tid * 8 + i * 4096);
        }
        __builtin_amdgcn_sched_barrier(0);

        // ---- gh GEMM: pure LDS(hA) + VGPR(warr); zero global consumption
        f32x4 zero4 = {0.f, 0.f, 0.f, 0.f};
        f32x4 acc[6];
#pragma unroll
        for (int fi = 0; fi < 6; ++fi) acc[fi] = zero4;
#pragma unroll
        for (int kt = 0; kt < 8; ++kt) {
            bf16x8 af = *(const bf16x8*)&hA[hA_off(lm, kt, lq)];
#pragma unroll
            for (int fi = 0; fi < 6; ++fi)
                acc[fi] = __builtin_amdgcn_mfma_f32_16x16x32_bf16(af, warr[fi][kt], acc[fi], 0, 0, 0);
        }
        // store only real rows (0-7): lq<2 <=> lq*4+rr < 8
        if (lq < 2) {
#pragma unroll
            for (int fi = 0; fi < 6; ++fi)
#pragma unroll
                for (int rr = 0; rr < 4; ++rr)
                    gh_s[lq * 4 + rr][jw2 + fi * 16 + lm] = acc[fi][rr] + bn[fi];
        }

        // barrier (1): gh_s ready; current slab guaranteed done (older than the
        // 3 in-flight prefetch loads) -> counted vmcnt keeps prefetch flying.
        if (sc + 1 < C) { asm volatile("s_waitcnt vmcnt(3) lgkmcnt(0)" ::: "memory"); }
        else            { asm volatile("s_waitcnt vmcnt(0) lgkmcnt(0)" ::: "memory"); }
        __builtin_amdgcn_s_barrier();
        __builtin_amdgcn_sched_barrier(0);

        // ---- combine: wave w = seq w; lane handles feats 2l+128j (+1), j=0,1
        const u32* grow = (const u32*)&geL[cur][w][0];
        float yv = 0.f;
#pragma unroll
        for (int j = 0; j < 2; ++j) {
            u32 g1r = grow[      l + 64 * j];
            u32 g1z = grow[128 + l + 64 * j];
            u32 g1n = grow[256 + l + 64 * j];
            u32 g2r = grow[384 + l + 64 * j];
            u32 g2z = grow[512 + l + 64 * j];
            u32 g2n = grow[640 + l + 64 * j];
            const int d0 = 2 * l + 128 * j;
            float2 ghr = *(const float2*)&gh_s[w][d0];
            float2 ghz = *(const float2*)&gh_s[w][256 + d0];
            float2 ghn = *(const float2*)&gh_s[w][512 + d0];
            float ir_lo = fmaf(m_w, blo(g2r), blo(g1r));
            float ir_hi = fmaf(m_w, bhi(g2r), bhi(g1r));
            float iz_lo = fmaf(m_w, blo(g2z), blo(g1z));
            float iz_hi = fmaf(m_w, bhi(g2z), bhi(g1z));
            float in_lo = fmaf(m_w, blo(g2n), blo(g1n));
            float in_hi = fmaf(m_w, bhi(g2n), bhi(g1n));
            float r_lo = sigm_(ir_lo + ghr.x);
            float r_hi = sigm_(ir_hi + ghr.y);
            float z_lo = sigm_(iz_lo + ghz.x);
            float z_hi = sigm_(iz_hi + ghz.y);
            float n_lo = tanh_(fmaf(r_lo, ghn.x, in_lo));
            float n_hi = tanh_(fmaf(r_hi, ghn.y, in_hi));
            float hn_lo = fmaf(z_lo, h_reg[2 * j] - n_lo, n_lo);
            float hn_hi = fmaf(z_hi, h_reg[2 * j + 1] - n_hi, n_hi);
            h_reg[2 * j] = hn_lo; h_reg[2 * j + 1] = hn_hi;
            int ktw = (l >> 4) + 4 * j, lq2 = (l >> 2) & 3;
            u32 pk = (u32)f2bf(hn_lo) | ((u32)f2bf(hn_hi) << 16);
            *(u32*)&hA[hA_off(w, ktw, lq2) + 2 * (l & 3)] = pk;
            yv += hn_lo * wo[2 * j] + hn_hi * wo[2 * j + 1];
        }
#pragma unroll
        for (int off = 32; off > 0; off >>= 1) yv += __shfl_xor(yv, off, 64);
        float y = yv + bo;
        if (l == 0) out[(size_t)nw * SLATE + (s0 + sc)] = y;
        m_w = sigm_(y);

        // barrier (2): hA visible for next GEMM; gh_s/geL reads done (WAR).
        // No vmcnt wait: prefetch keeps streaming.
        asm volatile("s_waitcnt lgkmcnt(0)" ::: "memory");
        __builtin_amdgcn_s_barrier();
        __builtin_amdgcn_sched_barrier(0);
    }

    // ---- persist state ----
#pragma unroll
    for (int j = 0; j < 2; ++j) {
        float2 v; v.x = h_reg[2 * j]; v.y = h_reg[2 * j + 1];
        *(float2*)&h_g[(size_t)nw * DD + 2 * l + 128 * j] = v;
    }
    if (l == 0) m_g[nw] = m_w;
}

extern "C" void kernel_launch(void* const* d_in, const int* in_sizes, int n_in,
                              void* d_out, int out_size, void* d_ws, size_t ws_size,
                              hipStream_t stream) {
    const int*   item_idxs  = (const int*)d_in[0];
    const int*   user_idxs  = (const int*)d_in[1];
    const float* item_table = (const float*)d_in[3];
    const float* user_table = (const float*)d_in[4];
    const float* W_ih       = (const float*)d_in[5];
    const float* W_hh       = (const float*)d_in[6];
    const float* b_ih       = (const float*)d_in[7];
    const float* b_hh       = (const float*)d_in[8];
    const float* W_out      = (const float*)d_in[9];
    const float* b_out      = (const float*)d_in[10];
    float* out = (float*)d_out;

    // ws: Ge (C*12 MiB) | e_bf (C*2 MiB) | W12 | Whh | h_g | m_g
    // C=10 max (C=20 thrashes L3: R5 post-mortem).
    const size_t fixed = 786432ull + 393216ull + 4194304ull + 16384ull;
    static const int cands[5] = {10, 5, 4, 2, 1};
    int C = 1;
    for (int i = 0; i < 5; ++i) {
        size_t need = (size_t)cands[i] * (12582912ull + 2097152ull) + fixed;
        if (need <= ws_size) { C = cands[i]; break; }
    }

    u16*   Ge   = (u16*)d_ws;
    u16*   e_bf = (u16*)((char*)d_ws + (size_t)C * 12582912ull);
    u16*   W12  = (u16*)((char*)e_bf + (size_t)C * 2097152ull);
    u16*   Whh  = (u16*)((char*)W12 + 786432ull);
    float* h_g  = (float*)((char*)Whh + 393216ull);
    float* m_g  = (float*)((char*)h_g + 4194304ull);

    prep_w<<<2304, 256, 0, stream>>>(W_ih, W_hh, W12, Whh);

    for (int s0 = 0; s0 < SLATE; s0 += C) {
        gather_e<<<C * 1024, 256, 0, stream>>>(s0, item_idxs, item_table, e_bf);
        dim3 gg(12, 32 * C);
        gemm_e<<<gg, 256, 0, stream>>>(e_bf, W12, b_ih, b_hh, Ge);
        seq_kernel<<<512, 512, 0, stream>>>(s0, C, Ge, Whh, user_idxs, user_table,
                                            b_hh, W_out, b_out, h_g, m_g, out);
    }
}

// Round 8
// 396.463 us; speedup vs baseline: 1.1391x; 1.1391x over previous
//
#include <hip/hip_runtime.h>
#include <math.h>

#define SLATE 20
#define DD 256
#define NSEQ 4096

typedef __attribute__((ext_vector_type(8))) short bf16x8;
typedef __attribute__((ext_vector_type(4))) float f32x4;
typedef unsigned short u16;
typedef unsigned int u32;

__device__ __forceinline__ u16 f2bf(float f) {
    unsigned u = __float_as_uint(f);
    u += 0x7fff + ((u >> 16) & 1);   // RNE
    return (u16)(u >> 16);
}
__device__ __forceinline__ float blo(u32 u) { return __uint_as_float(u << 16); }
__device__ __forceinline__ float bhi(u32 u) { return __uint_as_float(u & 0xffff0000u); }
// HW transcendentals: saturate correctly at +-inf, no NaN
__device__ __forceinline__ float sigm_(float x) {
    return __builtin_amdgcn_rcpf(1.f + __builtin_amdgcn_exp2f(-1.44269504f * x));
}
__device__ __forceinline__ float tanh_(float x) {
    return 1.f - 2.f * __builtin_amdgcn_rcpf(1.f + __builtin_amdgcn_exp2f(2.88539008f * x));
}

// async global->LDS, 16B per lane
__device__ __forceinline__ void gl_lds16(const void* g, void* l) {
    __builtin_amdgcn_global_load_lds(
        (const __attribute__((address_space(1))) unsigned int*)g,
        (__attribute__((address_space(3))) unsigned int*)l, 16, 0, 0);
}

// ---- prep: W12[j<768][k]=W_ih[j][k]; W12[768+j][k]=W_ih[j][256+k]; Whh bf16
__global__ void prep_w(const float* __restrict__ W_ih, const float* __restrict__ W_hh,
                       u16* __restrict__ W12, u16* __restrict__ Whh) {
    int i = blockIdx.x * 256 + threadIdx.x;
    if (i < 1536 * 256) {
        int j = i >> 8, k = i & 255;
        float v = (j < 768) ? W_ih[(size_t)j * 512 + k]
                            : W_ih[(size_t)(j - 768) * 512 + 256 + k];
        W12[i] = f2bf(v);
    } else {
        int i2 = i - 1536 * 256;
        Whh[i2] = f2bf(W_hh[i2]);
    }
}

// ---- gather chunk embeddings to bf16, M-order = [s_local][n]
__global__ void gather_e(int s0, const int* __restrict__ idxs, const float* __restrict__ itab,
                         u16* __restrict__ e_bf) {
    int g = blockIdx.x * 256 + threadIdx.x;
    int row = g >> 6, c = g & 63;
    int n = row & (NSEQ - 1), s = s0 + (row >> 12);
    int idx = idxs[n * SLATE + s];
    float4 v = *(const float4*)&itab[(size_t)idx * DD + c * 4];
    ushort4 o;
    o.x = f2bf(v.x); o.y = f2bf(v.y); o.z = f2bf(v.z); o.w = f2bf(v.w);
    *(ushort4*)&e_bf[(size_t)row * DD + c * 4] = o;
}

// ---- hoisted GEMM: EXACT R2 code (measured 65 us) with ONE delta:
// __launch_bounds__(256, 4) caps unified regs at 128/thread (acc=64 AGPR -> V must
// fit 64), raising the residency cap from 3 to 4 blocks/CU. The per-K-step
// stage->drain->compute structure is hidden ONLY by co-resident blocks, and R2
// measured 27% occupancy (reg-limited ~3 blocks peak). No code restructure:
// every restructure attempt (depth-2, 256-tile, uint2 epilogue, XCD swizzle)
// measured worse. Epilogue folds b_ih (cols<768) + b_hh (r,z cols<512).
__global__ __launch_bounds__(256, 4) void gemm_e(
        const u16* __restrict__ e_bf, const u16* __restrict__ W12,
        const float* __restrict__ b_ih, const float* __restrict__ b_hh,
        u16* __restrict__ Ge) {
    __shared__ u16 A_s[128][32];
    __shared__ u16 B_s[128][32];

    const int tid = threadIdx.x;
    const int w = tid >> 6, l = tid & 63, lm = l & 15, lq = l >> 4;
    const int wm = w & 1, wn = w >> 1;
    const size_t m0 = (size_t)blockIdx.y * 128;
    const size_t n0 = (size_t)blockIdx.x * 128;

    f32x4 acc[4][4];
    f32x4 zero4 = {0.f, 0.f, 0.f, 0.f};
#pragma unroll
    for (int mi = 0; mi < 4; ++mi)
#pragma unroll
        for (int nj = 0; nj < 4; ++nj) acc[mi][nj] = zero4;

    const int srow = w * 16 + (l >> 2);
    const int skc = (l & 3) * 8;
    const u16* gA = e_bf + (m0 + srow) * DD + skc;
    const u16* gB = W12 + (n0 + srow) * DD + skc;
    u16* lA = &A_s[0][0] + w * 512 + l * 8;
    u16* lB = &B_s[0][0] + w * 512 + l * 8;

    for (int kt = 0; kt < 8; ++kt) {
        const int ko = kt * 32;
        gl_lds16(gA + ko, lA);
        gl_lds16(gA + 64 * DD + ko, lA + 2048);
        gl_lds16(gB + ko, lB);
        gl_lds16(gB + 64 * DD + ko, lB + 2048);
        __syncthreads();
        bf16x8 af[4], bfr[4];
#pragma unroll
        for (int mi = 0; mi < 4; ++mi)
            af[mi] = *(const bf16x8*)&A_s[wm * 64 + mi * 16 + lm][lq * 8];
#pragma unroll
        for (int nj = 0; nj < 4; ++nj)
            bfr[nj] = *(const bf16x8*)&B_s[wn * 64 + nj * 16 + lm][lq * 8];
#pragma unroll
        for (int nj = 0; nj < 4; ++nj)
#pragma unroll
            for (int mi = 0; mi < 4; ++mi)
                acc[mi][nj] = __builtin_amdgcn_mfma_f32_16x16x32_bf16(af[mi], bfr[nj], acc[mi][nj], 0, 0, 0);
        __syncthreads();
    }
    float bb[4];
#pragma unroll
    for (int nj = 0; nj < 4; ++nj) {
        int col = (int)n0 + wn * 64 + nj * 16 + lm;
        bb[nj] = 0.f;
        if (col < 768) bb[nj] = b_ih[col] + (col < 512 ? b_hh[col] : 0.f);
    }
#pragma unroll
    for (int mi = 0; mi < 4; ++mi)
#pragma unroll
        for (int rr = 0; rr < 4; ++rr) {
            u16* gp = Ge + (m0 + wm * 64 + mi * 16 + lq * 4 + rr) * 1536 + n0 + wn * 64 + lm;
#pragma unroll
            for (int nj = 0; nj < 4; ++nj) gp[nj * 16] = f2bf(acc[mi][nj][rr] + bb[nj]);
        }
}

// swizzled hA: logical (seq, k) -> u16 offset; v spreads banks for both access patterns
__device__ __forceinline__ int hA_off(int seq, int kt, int lq2) {
    int v = ((kt & 3) << 2) | lq2;
    return kt * 512 + lq2 * 128 + ((seq ^ v) << 3);
}

// ---- fused sequential kernel: R2-EXACT (the 399us-total config; R7's 8-seq
// split measured WORSE: LDS 80KB still gave 1 block/CU - occupancy 21.9%).
// 256 blocks x 16 seqs, 512 threads (8 waves). Steady-state GEMM is 100%
// {VGPR, LDS}-sourced; only vmcnt ops per step are the 6 global_load_lds
// prefetching the NEXT step's Ge slab -> counted vmcnt(6) keeps them in
// flight across barriers (full-step latency cover).
__global__ __launch_bounds__(512, 2) void seq_kernel(
        int s0, int C,
        const u16* __restrict__ Ge,     // [C*4096][1536] (b_ih + b_hh(r,z) pre-folded)
        const u16* __restrict__ Whh,    // [768][256] bf16
        const int* __restrict__ user_idxs, const float* __restrict__ user_table,
        const float* __restrict__ b_hh,
        const float* __restrict__ W_out, const float* __restrict__ b_out,
        float* __restrict__ h_g, float* __restrict__ m_g, float* __restrict__ out)
{
    __shared__ u16   hA[4096];          // 8 KB, swizzled h (16 seqs x 256 k, bf16)
    __shared__ float gh_s[16][770];     // 48.1 KB
    __shared__ u16   geL[2][16][1536];  // 96 KB double-buffered Ge slab

    const int tid = threadIdx.x;
    const int w = tid >> 6, l = tid & 63, lm = l & 15, lq = l >> 4;
    const int l5 = l & 31, sh = l >> 5;
    const int n0 = blockIdx.x * 16;
    const int sloc = 2 * w + sh;        // combine: each wave finishes 2 seqs
    const int nw = n0 + sloc;
    const int jw2 = w * 96;             // GEMM: each wave owns 96 N-cols

    // ---- Whh fully VGPR-resident: 6 fragments x 8 k-steps = 192 regs
    bf16x8 warr[6][8];
    const u16* wb = Whh + (size_t)(jw2 + lm) * DD + lq * 8;
#pragma unroll
    for (int fi = 0; fi < 6; ++fi)
#pragma unroll
        for (int kt = 0; kt < 8; ++kt)
            warr[fi][kt] = *(const bf16x8*)(wb + fi * 16 * DD + kt * 32);

    // gate-n b_hh (cols >= 512 only; wave-uniform condition per fragment)
    float bn[6];
#pragma unroll
    for (int fi = 0; fi < 6; ++fi) {
        int colb = jw2 + fi * 16;
        bn[fi] = (colb >= 512) ? b_hh[colb + lm] : 0.f;
    }

    // W_out per-lane (lane's 8 features: 2*l5+64j, +1)
    float wo[8];
#pragma unroll
    for (int j = 0; j < 4; ++j) {
        float2 t = *(const float2*)&W_out[2 * l5 + 64 * j];
        wo[2 * j] = t.x; wo[2 * j + 1] = t.y;
    }
    const float bo = b_out[0];

    // ---- init h (8 feats/lane) ----
    float h_reg[8]; float m_w;
    if (s0 == 0) {
        const float* hu = user_table + (size_t)user_idxs[nw] * DD;
#pragma unroll
        for (int j = 0; j < 4; ++j) {
            float2 t = *(const float2*)&hu[2 * l5 + 64 * j];
            h_reg[2 * j] = t.x; h_reg[2 * j + 1] = t.y;
        }
        m_w = 1.f;
    } else {
        const float* hp = h_g + (size_t)nw * DD;
#pragma unroll
        for (int j = 0; j < 4; ++j) {
            float2 t = *(const float2*)&hp[2 * l5 + 64 * j];
            h_reg[2 * j] = t.x; h_reg[2 * j + 1] = t.y;
        }
        m_w = m_g[nw];
    }
    // hA init: k = 2*l5 + 64*j maps to (kt=(l5>>4)+2j, lq2=(l5&15)>>2, pos=2*(l5&3))
#pragma unroll
    for (int j = 0; j < 4; ++j) {
        int ktw = (l5 >> 4) + 2 * j, lq2 = (l5 & 15) >> 2;
        u32 pk = (u32)f2bf(h_reg[2 * j]) | ((u32)f2bf(h_reg[2 * j + 1]) << 16);
        *(u32*)&hA[hA_off(sloc, ktw, lq2) + 2 * (l5 & 3)] = pk;
    }

    // ---- prologue: stage slab 0 (48 KB contiguous, 6 x 16B per thread)
    {
        const u16* g0 = Ge + (size_t)n0 * 1536;
        u16* l0 = &geL[0][0][0];
#pragma unroll
        for (int i = 0; i < 6; ++i)
            gl_lds16(g0 + tid * 8 + i * 4096, l0 + tid * 8 + i * 4096);
    }
    asm volatile("s_waitcnt lgkmcnt(0)" ::: "memory");
    __builtin_amdgcn_s_barrier();
    __builtin_amdgcn_sched_barrier(0);

    for (int sc = 0; sc < C; ++sc) {
        const int cur = sc & 1;

        // ---- prefetch NEXT step's slab at top of step: full-step cover
        if (sc + 1 < C) {
            const u16* gn = Ge + ((size_t)(sc + 1) * NSEQ + n0) * 1536;
            u16* ln = &geL[cur ^ 1][0][0];
#pragma unroll
            for (int i = 0; i < 6; ++i)
                gl_lds16(gn + tid * 8 + i * 4096, ln + tid * 8 + i * 4096);
        }
        __builtin_amdgcn_sched_barrier(0);

        // ---- gh GEMM: pure LDS(hA) + VGPR(warr); zero global consumption
        f32x4 zero4 = {0.f, 0.f, 0.f, 0.f};
        f32x4 acc[6];
#pragma unroll
        for (int fi = 0; fi < 6; ++fi) acc[fi] = zero4;
#pragma unroll
        for (int kt = 0; kt < 8; ++kt) {
            bf16x8 af = *(const bf16x8*)&hA[hA_off(lm, kt, lq)];
#pragma unroll
            for (int fi = 0; fi < 6; ++fi)
                acc[fi] = __builtin_amdgcn_mfma_f32_16x16x32_bf16(af, warr[fi][kt], acc[fi], 0, 0, 0);
        }
#pragma unroll
        for (int fi = 0; fi < 6; ++fi)
#pragma unroll
            for (int rr = 0; rr < 4; ++rr)
                gh_s[lq * 4 + rr][jw2 + fi * 16 + lm] = acc[fi][rr] + bn[fi];

        // barrier (1): gh_s ready; current slab guaranteed done (it is older than
        // the 6 in-flight prefetch loads) -> counted vmcnt keeps prefetch flying.
        if (sc + 1 < C) { asm volatile("s_waitcnt vmcnt(6) lgkmcnt(0)" ::: "memory"); }
        else            { asm volatile("s_waitcnt vmcnt(0) lgkmcnt(0)" ::: "memory"); }
        __builtin_amdgcn_s_barrier();
        __builtin_amdgcn_sched_barrier(0);

        // ---- combine: lane handles seq sloc, feats 2*l5+64j (+1), j=0..3
        const u32* grow = (const u32*)&geL[cur][sloc][0];
        float yv = 0.f;
#pragma unroll
        for (int j = 0; j < 4; ++j) {
            u32 g1r = grow[      l5 + 32 * j];
            u32 g1z = grow[128 + l5 + 32 * j];
            u32 g1n = grow[256 + l5 + 32 * j];
            u32 g2r = grow[384 + l5 + 32 * j];
            u32 g2z = grow[512 + l5 + 32 * j];
            u32 g2n = grow[640 + l5 + 32 * j];
            const int d0 = 2 * l5 + 64 * j;
            float2 ghr = *(const float2*)&gh_s[sloc][d0];
            float2 ghz = *(const float2*)&gh_s[sloc][256 + d0];
            float2 ghn = *(const float2*)&gh_s[sloc][512 + d0];
            float ir_lo = fmaf(m_w, blo(g2r), blo(g1r));
            float ir_hi = fmaf(m_w, bhi(g2r), bhi(g1r));
            float iz_lo = fmaf(m_w, blo(g2z), blo(g1z));
            float iz_hi = fmaf(m_w, bhi(g2z), bhi(g1z));
            float in_lo = fmaf(m_w, blo(g2n), blo(g1n));
            float in_hi = fmaf(m_w, bhi(g2n), bhi(g1n));
            float r_lo = sigm_(ir_lo + ghr.x);
            float r_hi = sigm_(ir_hi + ghr.y);
            float z_lo = sigm_(iz_lo + ghz.x);
            float z_hi = sigm_(iz_hi + ghz.y);
            float n_lo = tanh_(fmaf(r_lo, ghn.x, in_lo));
            float n_hi = tanh_(fmaf(r_hi, ghn.y, in_hi));
            float hn_lo = fmaf(z_lo, h_reg[2 * j] - n_lo, n_lo);
            float hn_hi = fmaf(z_hi, h_reg[2 * j + 1] - n_hi, n_hi);
            h_reg[2 * j] = hn_lo; h_reg[2 * j + 1] = hn_hi;
            int ktw = (l5 >> 4) + 2 * j, lq2 = (l5 & 15) >> 2;
            u32 pk = (u32)f2bf(hn_lo) | ((u32)f2bf(hn_hi) << 16);
            *(u32*)&hA[hA_off(sloc, ktw, lq2) + 2 * (l5 & 3)] = pk;
            yv += hn_lo * wo[2 * j] + hn_hi * wo[2 * j + 1];
        }
#pragma unroll
        for (int off = 16; off > 0; off >>= 1) yv += __shfl_xor(yv, off, 32);
        float y = yv + bo;
        if (l5 == 0) out[(size_t)nw * SLATE + (s0 + sc)] = y;
        m_w = sigm_(y);

        // barrier (2): hA visible for next GEMM; gh_s/geL reads done (WAR).
        // No vmcnt wait: prefetch keeps streaming.
        asm volatile("s_waitcnt lgkmcnt(0)" ::: "memory");
        __builtin_amdgcn_s_barrier();
        __builtin_amdgcn_sched_barrier(0);
    }

    // ---- persist state ----
#pragma unroll
    for (int j = 0; j < 4; ++j) {
        float2 v; v.x = h_reg[2 * j]; v.y = h_reg[2 * j + 1];
        *(float2*)&h_g[(size_t)nw * DD + 2 * l5 + 64 * j] = v;
    }
    if (l5 == 0) m_g[nw] = m_w;
}

extern "C" void kernel_launch(void* const* d_in, const int* in_sizes, int n_in,
                              void* d_out, int out_size, void* d_ws, size_t ws_size,
                              hipStream_t stream) {
    const int*   item_idxs  = (const int*)d_in[0];
    const int*   user_idxs  = (const int*)d_in[1];
    const float* item_table = (const float*)d_in[3];
    const float* user_table = (const float*)d_in[4];
    const float* W_ih       = (const float*)d_in[5];
    const float* W_hh       = (const float*)d_in[6];
    const float* b_ih       = (const float*)d_in[7];
    const float* b_hh       = (const float*)d_in[8];
    const float* W_out      = (const float*)d_in[9];
    const float* b_out      = (const float*)d_in[10];
    float* out = (float*)d_out;

    // ws: Ge (C*12 MiB) | e_bf (C*2 MiB) | W12 | Whh | h_g | m_g
    // C=10 max (C=20 thrashes L3: R5 post-mortem).
    const size_t fixed = 786432ull + 393216ull + 4194304ull + 16384ull;
    static const int cands[5] = {10, 5, 4, 2, 1};
    int C = 1;
    for (int i = 0; i < 5; ++i) {
        size_t need = (size_t)cands[i] * (12582912ull + 2097152ull) + fixed;
        if (need <= ws_size) { C = cands[i]; break; }
    }

    u16*   Ge   = (u16*)d_ws;
    u16*   e_bf = (u16*)((char*)d_ws + (size_t)C * 12582912ull);
    u16*   W12  = (u16*)((char*)e_bf + (size_t)C * 2097152ull);
    u16*   Whh  = (u16*)((char*)W12 + 786432ull);
    float* h_g  = (float*)((char*)Whh + 393216ull);
    float* m_g  = (float*)((char*)h_g + 4194304ull);

    prep_w<<<2304, 256, 0, stream>>>(W_ih, W_hh, W12, Whh);

    for (int s0 = 0; s0 < SLATE; s0 += C) {
        gather_e<<<C * 1024, 256, 0, stream>>>(s0, item_idxs, item_table, e_bf);
        dim3 gg(12, 32 * C);
        gemm_e<<<gg, 256, 0, stream>>>(e_bf, W12, b_ih, b_hh, Ge);
        seq_kernel<<<256, 512, 0, stream>>>(s0, C, Ge, Whh, user_idxs, user_table,
                                            b_hh, W_out, b_out, h_g, m_g, out);
    }
}